// Round 9
// baseline (262.651 us; speedup 1.0000x reference)
//
#include <hip/hip_runtime.h>

// Guided filter fused kernel, round 11: r5 base + role-split tail phase.
// (16,3,512,512) fp32, r=8 (17x17 box, zero 'same' padding, analytic N).
//
// Ledger: r5=155us (best), r7(-work)=159, r9b(+occ)=222, r10b(T14)=174.
// r10b lesson: hipcc drains vmcnt(0) before every s_barrier, so loads cannot
// usefully span a __syncthreads.  This round keeps loads INSIDE one phase but
// overlaps that phase with independent work in OTHER waves:
//
//   tail phase (one per group, replaces r5's stage;s5;bar;s2 = 2 phases):
//     waves 0-3 (tid<256): fused stage+s2 for the 32 new rows.  Each 8-lane
//       group stages its row's 16 granules (4x dwordx4 + 4 ds_write) then
//       immediately runs s2 on that same row -> the write->read dependency is
//       INTRA-WAVE (compiler lgkmcnt), no barrier.
//     waves 4-7: s5 (4 rows/thread).  Stage vmcnt stalls only waves 0-3;
//       waves 4-7 keep the VALU/global pipes busy meanwhile.
//   Barriers/group: 4 -> 3.
//
// Hazards (all re-derived): s2(g) writes ring slots (32g+64)&63.. whose last
// reader was s3(g), two barriers earlier.  stage writes F4 bytes [0,16384)
// after s4's barrier (AB reads done); s5 reads HAB bytes [19200,31872) --
// disjoint, concurrent OK.  s2(g) vs s3(g+1): loop-top barrier.  Next-reader
// s3(g+1) of new ring rows: loop-top barrier.
//
// LDS = exactly 80 KiB -> 2 blocks/CU:
//   F4 : region (I,p) float4 granules [64][32], phys g^(row&7), halves
//        swapped iff row&1.  After s2, same space: AB (48 x stride 50
//        float2), HAB (48 x stride 33 float2 at byte 19200).
//   H4 : H-sums (sI,sp,sIp,sII) float4 ring [64][48], phys col^(row&7).
// Ring slot = row&63; slot&7 == row&7 (group offsets multiple of 32).

#define RAD  8
#define H    512
#define W    512
#define TILE 32
#define KCH  4
#define EPS  0.01f

__global__ __launch_bounds__(512, 4)
void guided_filter_kernel(const float* __restrict__ Ig,
                          const float* __restrict__ Pg,
                          float* __restrict__ out)
{
    __shared__ __align__(16) float4 F4[64 * 32];   // 32768 B
    __shared__ __align__(16) float4 H4[64 * 48];   // 49152 B (ring)

    float2* F2p = (float2*)F4;
    float2* AB  = (float2*)F4;                 // 48 rows x stride 50 (19200 B)
    float2* HAB = (float2*)F4 + 48 * 50;       // 48 rows x stride 33 (12672 B)

    const int tid   = threadIdx.x;
    const int plane = blockIdx.z;
    const int x0 = blockIdx.x * TILE - 2 * RAD;
    const int Y0 = blockIdx.y * (TILE * KCH);
    const float* Ib = Ig + (size_t)plane * (H * W);
    const float* Pb = Pg + (size_t)plane * (H * W);
    float* Ob = out + (size_t)plane * (H * W);

    // ---- shared s2 row body: horizontal 17-sums of F4 row r -> ring ----
    auto s2_row = [&](int r, int e, int tbase) {
        const int rl = r & 7, pf = r & 1;
        const int c0 = 6 * e;
        const float4* Fr = &F4[r * 32];
        const float2* Er = &F2p[r * 64];
        float4 S = make_float4(0.f, 0.f, 0.f, 0.f);
        const int gb = 3 * e;
        #pragma unroll
        for (int m = 0; m < 8; ++m) {   // elements c0 .. c0+15
            float4 fr = Fr[(gb + m) ^ rl];
            S.x += fr.x + fr.z;
            S.y += fr.y + fr.w;
            S.z += fr.x * fr.y + fr.z * fr.w;
            S.w += fr.x * fr.x + fr.z * fr.z;
        }
        {
            int c = c0 + 16;            // even -> within-granule slot = pf
            float2 v = Er[(((c >> 1) ^ rl) << 1) | pf];
            S.x += v.x; S.y += v.y; S.z += v.x * v.y; S.w += v.x * v.x;
        }
        const int slot = (tbase + r) & 63;   // slot&7 == r&7 (tbase % 32 == 0)
        float4* Hrow = &H4[slot * 48];
        #pragma unroll
        for (int k = 0; k < 6; ++k) {
            Hrow[(c0 + k) ^ rl] = S;
            if (k < 5) {
                int ca = c0 + k + 17, cs = c0 + k;
                float2 va = Er[(((ca >> 1) ^ rl) << 1) | ((ca & 1) ^ pf)];
                float2 vs = Er[(((cs >> 1) ^ rl) << 1) | ((cs & 1) ^ pf)];
                S.x += va.x - vs.x;
                S.y += va.y - vs.y;
                S.z += va.x * va.y - vs.x * vs.y;
                S.w += va.x * va.x - vs.x * vs.x;
            }
        }
    };

    // ---- Prologue stage: raw rows [ybase, ybase+64) -> F4 (512 thr) ----
    auto stage_raw64 = [&](int ybase) {
        const bool interior = (x0 >= 0) && (ybase >= 0) &&
                              (x0 + 64 <= W) && (ybase + 64 <= H);
        if (interior) {
            #pragma unroll
            for (int it = 0; it < 2; ++it) {
                int idx = it * 512 + tid;
                int ry = idx >> 4, f4 = idx & 15;
                int rl = ry & 7, pf = ry & 1;
                const float* ip = Ib + (ybase + ry) * W + x0 + 4 * f4;
                const float* pp = Pb + (ybase + ry) * W + x0 + 4 * f4;
                float4 iv = *(const float4*)ip;
                float4 pv = *(const float4*)pp;
                float2 e0 = make_float2(iv.x, pv.x), e1 = make_float2(iv.y, pv.y);
                float2 e2 = make_float2(iv.z, pv.z), e3 = make_float2(iv.w, pv.w);
                float2 a0 = pf ? e1 : e0, a1 = pf ? e0 : e1;
                float2 b0 = pf ? e3 : e2, b1 = pf ? e2 : e3;
                float4* Fr = &F4[ry * 32];
                Fr[(2 * f4) ^ rl]     = make_float4(a0.x, a0.y, a1.x, a1.y);
                Fr[(2 * f4 + 1) ^ rl] = make_float4(b0.x, b0.y, b1.x, b1.y);
            }
        } else {
            #pragma unroll
            for (int it = 0; it < 2; ++it) {
                int idx = it * 512 + tid;
                int ry = idx >> 4, f4 = idx & 15;
                int rl = ry & 7, pf = ry & 1;
                int gy = ybase + ry;
                float2 el[4];
                #pragma unroll
                for (int k = 0; k < 4; ++k) {
                    int gx = x0 + 4 * f4 + k;
                    bool v = ((unsigned)gy < (unsigned)H) && ((unsigned)gx < (unsigned)W);
                    el[k].x = v ? Ib[gy * W + gx] : 0.f;
                    el[k].y = v ? Pb[gy * W + gx] : 0.f;
                }
                float2 a0 = pf ? el[1] : el[0], a1 = pf ? el[0] : el[1];
                float2 b0 = pf ? el[3] : el[2], b1 = pf ? el[2] : el[3];
                float4* Fr = &F4[ry * 32];
                Fr[(2 * f4) ^ rl]     = make_float4(a0.x, a0.y, a1.x, a1.y);
                Fr[(2 * f4 + 1) ^ rl] = make_float4(b0.x, b0.y, b1.x, b1.y);
            }
        }
    };

    // ---- Fused tail A (tid<256): stage 32 new rows + s2 them, intra-wave ----
    // Thread (ry = tid>>3, sub = tid&7): stages f4 positions {2sub, 2sub+1} of
    // row ry, then runs s2 on row ry (cols [6sub, 6sub+6)).  Row ry is staged
    // entirely by lanes ry*8..ry*8+7 -> s2's reads of row ry are intra-wave.
    auto tail_stage_s2 = [&](int g) {
        const int ry = tid >> 3, sub = tid & 7;
        const int ybase = Y0 + 32 * g + 48;
        const int rl = ry & 7, pf = ry & 1;
        const int gy = ybase + ry;
        const bool interior = (x0 >= 0) && (x0 + 64 <= W) &&
                              (ybase >= 0) && (ybase + 32 <= H);
        float4* Fr = &F4[ry * 32];
        #pragma unroll
        for (int h = 0; h < 2; ++h) {
            const int f4 = 2 * sub + h;
            float4 iv, pv;
            if (interior) {
                iv = *(const float4*)(Ib + gy * W + x0 + 4 * f4);
                pv = *(const float4*)(Pb + gy * W + x0 + 4 * f4);
            } else {
                float* fi = (float*)&iv;
                float* fp = (float*)&pv;
                #pragma unroll
                for (int k = 0; k < 4; ++k) {
                    int gx = x0 + 4 * f4 + k;
                    bool v = ((unsigned)gy < (unsigned)H) && ((unsigned)gx < (unsigned)W);
                    fi[k] = v ? Ib[gy * W + gx] : 0.f;
                    fp[k] = v ? Pb[gy * W + gx] : 0.f;
                }
            }
            float2 e0 = make_float2(iv.x, pv.x), e1 = make_float2(iv.y, pv.y);
            float2 e2 = make_float2(iv.z, pv.z), e3 = make_float2(iv.w, pv.w);
            float2 a0 = pf ? e1 : e0, a1 = pf ? e0 : e1;
            float2 b0 = pf ? e3 : e2, b1 = pf ? e2 : e3;
            Fr[(2 * f4) ^ rl]     = make_float4(a0.x, a0.y, a1.x, a1.y);
            Fr[(2 * f4 + 1) ^ rl] = make_float4(b0.x, b0.y, b1.x, b1.y);
        }
        // s2 on the just-staged row (intra-wave dependency only)
        s2_row(ry, sub, 32 * g + 64);
    };

    // ---- Stage 3: vertical 17-sums over H ring rows [32g, 32g+48) -> a,b ----
    auto s3g = [&](int g) {
        if (tid < 384) {
            const int col = tid % 48, chunk = tid / 48;
            const int cy0 = chunk * 6;
            const int tb = 32 * g;
            float4 S = make_float4(0.f, 0.f, 0.f, 0.f);
            #pragma unroll
            for (int j = 0; j < 17; ++j) {
                int row = tb + cy0 + j;
                float4 v = H4[(row & 63) * 48 + (col ^ (row & 7))];
                S.x += v.x; S.y += v.y; S.z += v.z; S.w += v.w;
            }
            int gx = x0 + RAD + col;
            int nx = min(gx + RAD, W - 1) - max(gx - RAD, 0) + 1;
            #pragma unroll
            for (int k = 0; k < 6; ++k) {
                int cy = cy0 + k;
                int gy = Y0 + 32 * g - RAD + cy;
                float a = 0.f, b = 0.f;
                if (((unsigned)gy < (unsigned)H) && ((unsigned)gx < (unsigned)W)) {
                    int ny = min(gy + RAD, H - 1) - max(gy - RAD, 0) + 1;
                    float invN = __builtin_amdgcn_rcpf((float)(nx * ny));
                    float mI = S.x * invN, mp = S.y * invN;
                    float cov = S.z * invN - mI * mp;
                    float var = S.w * invN - mI * mI;
                    a = cov * __builtin_amdgcn_rcpf(var + EPS);
                    b = mp - a * mI;
                }
                AB[cy * 50 + col] = make_float2(a, b);
                if (k < 5) {
                    int ra = tb + cy + 17, rs = tb + cy;
                    float4 va = H4[(ra & 63) * 48 + (col ^ (ra & 7))];
                    float4 vs = H4[(rs & 63) * 48 + (col ^ (rs & 7))];
                    S.x += va.x - vs.x; S.y += va.y - vs.y;
                    S.z += va.z - vs.z; S.w += va.w - vs.w;
                }
            }
        }
    };

    // ---- Stage 4: horizontal 17-sums of a,b -> HAB ----
    auto s4 = [&]() {
        if (tid < 384) {
            const int r = tid % 48, e = tid / 48;   // e in 0..7, 4 output cols each
            const int c0 = 4 * e;
            const float2* row  = &AB[r * 50];
            const float4* rowg = (const float4*)row;   // rows 16B-aligned
            float2 S = make_float2(0.f, 0.f);
            #pragma unroll
            for (int m = 0; m < 8; ++m) {           // elements c0 .. c0+15
                float4 gq = rowg[2 * e + m];
                S.x += gq.x + gq.z;
                S.y += gq.y + gq.w;
            }
            {
                float2 v = row[c0 + 16];
                S.x += v.x; S.y += v.y;
            }
            #pragma unroll
            for (int k = 0; k < 4; ++k) {
                HAB[r * 33 + c0 + k] = S;
                if (k < 3) {
                    float2 va = row[c0 + k + 17];
                    float2 vs = row[c0 + k];
                    S.x += va.x - vs.x; S.y += va.y - vs.y;
                }
            }
        }
    };

    // ---- Stage 5 (tail B, tid>=256): vertical 17-sums of HAB -> q ----
    auto s5g = [&](int g) {
        const int t2 = tid - 256;
        const int col = t2 & 31, chunk = t2 >> 5;   // 8 chunks x 4 rows
        const int oy0 = chunk * 4;
        float2 S = make_float2(0.f, 0.f);
        #pragma unroll
        for (int j = 0; j < 17; ++j) {
            float2 v = HAB[(oy0 + j) * 33 + col];
            S.x += v.x; S.y += v.y;
        }
        int gx = x0 + 2 * RAD + col;
        int nx = min(gx + RAD, W - 1) - max(gx - RAD, 0) + 1;
        #pragma unroll
        for (int k = 0; k < 4; ++k) {
            int oy = oy0 + k;
            int gy = Y0 + 32 * g + oy;
            int ny = min(gy + RAD, H - 1) - max(gy - RAD, 0) + 1;
            float invN = __builtin_amdgcn_rcpf((float)(nx * ny));
            float iv = Ib[gy * W + gx];
            Ob[gy * W + gx] = S.x * invN * iv + S.y * invN;
            if (k < 3) {
                float2 va = HAB[(oy + 17) * 33 + col];
                float2 vs = HAB[oy * 33 + col];
                S.x += va.x - vs.x; S.y += va.y - vs.y;
            }
        }
    };

    // ---- Schedule ----
    stage_raw64(Y0 - 2 * RAD);            // raw rows t in [0,64)
    __syncthreads();
    s2_row(tid >> 3, tid & 7, 0);         // H ring slots 0..63 (512 thr)
    #pragma unroll 1
    for (int g = 0; g < KCH; ++g) {
        __syncthreads();                  // ring ready (s2 of prev tail done)
        s3g(g);                           // H ring -> AB (in F4 space)
        __syncthreads();
        s4();                             // AB -> HAB
        __syncthreads();
        if (tid < 256) {                  // tail A: stage+s2 (intra-wave)
            if (g < KCH - 1) tail_stage_s2(g);
        } else {                          // tail B: s5 -> out
            s5g(g);
        }
    }
}

extern "C" void kernel_launch(void* const* d_in, const int* in_sizes, int n_in,
                              void* d_out, int out_size, void* d_ws, size_t ws_size,
                              hipStream_t stream) {
    const float* I = (const float*)d_in[0];
    const float* P = (const float*)d_in[1];
    float* out = (float*)d_out;
    int planes = in_sizes[0] / (H * W);   // 48
    dim3 grid(W / TILE, H / (TILE * KCH), planes);
    guided_filter_kernel<<<grid, dim3(512), 0, stream>>>(I, P, out);
}